// Round 2
// baseline (352.825 us; speedup 1.0000x reference)
//
#include <hip/hip_runtime.h>
#include <hip/hip_bf16.h>
#include <stdint.h>

#define LSEQ 200
#define DDIM 128

typedef __attribute__((ext_vector_type(8))) __bf16 bf16x8;
typedef __attribute__((ext_vector_type(4))) float f32x4;

__device__ __forceinline__ float fast_exp(float x) {
  return __builtin_amdgcn_exp2f(x * 1.4426950408889634f);
}
__device__ __forceinline__ float fast_sigmoid(float x) {
  return __builtin_amdgcn_rcpf(1.0f + fast_exp(-x));
}
__device__ __forceinline__ float fast_tanh(float x) {
  float ax = __builtin_fabsf(x);
  float t = __builtin_amdgcn_exp2f(ax * -2.885390081777927f);  // exp(-2|x|)
  float r = (1.0f - t) * __builtin_amdgcn_rcpf(1.0f + t);
  return x < 0.0f ? -r : r;
}

__device__ __forceinline__ f32x4 mfma16(bf16x8 a, bf16x8 b, f32x4 c) {
  return __builtin_amdgcn_mfma_f32_16x16x32_bf16(a, b, c, 0, 0, 0);
}

// One recurrence step. XC holds A-frags of x_{t+1} (feeds next step's
// precomputed x-part accs AX*N); XN receives the prefetch of x_{t+2}.
// AX*C are the precomputed (biased) x-part gate accs for step t.
#define STEP(t, XC, XN, AXRC, AXUC, AXHC, AXRN, AXUN, AXHN)             \
  do {                                                                  \
    if ((t) + 2 < LSEQ) {                                               \
      size_t pbase = ((size_t)b16 * LSEQ + (t) + 2) * 4;                \
      _Pragma("unroll") for (int kt = 0; kt < 4; ++kt)                  \
          XN[kt] = xp[(pbase + kt) * 64 + lane];                        \
    }                                                                   \
    bf16x8 hf[4];                                                       \
    _Pragma("unroll") for (int kt = 0; kt < 4; ++kt)                    \
        hf[kt] = *(const bf16x8*)&s_hb[rA][kt * 32 + g * 8];            \
    f32x4 accr = AXRC, accu = AXUC;                                     \
    if ((t) + 1 < LSEQ) { /* build next step's x-part (indep MFMAs) */  \
      AXRN = (f32x4){biasr, biasr, biasr, biasr};                       \
      AXUN = (f32x4){biasu, biasu, biasu, biasu};                       \
      _Pragma("unroll") for (int kt = 0; kt < 4; ++kt) {                \
        bf16x8 a = __builtin_bit_cast(bf16x8, XC[kt]);                  \
        AXRN = mfma16(a, wr[kt], AXRN);                                 \
        AXUN = mfma16(a, wu[kt], AXUN);                                 \
      }                                                                 \
    }                                                                   \
    _Pragma("unroll") for (int kt = 0; kt < 4; ++kt) {                  \
      accr = mfma16(hf[kt], wr[4 + kt], accr);                          \
      accu = mfma16(hf[kt], wu[4 + kt], accu);                          \
    }                                                                   \
    float rr[4], uu[4];                                                 \
    _Pragma("unroll") for (int j = 0; j < 4; ++j) {                     \
      rr[j] = fast_sigmoid(accr[j]);                                    \
      uu[j] = fast_sigmoid(accu[j]);                                    \
      s_rh[g * 4 + j][col] = (__bf16)(rr[j] * hD[j]);                   \
    }                                                                   \
    __builtin_amdgcn_sched_barrier(0);                                  \
    asm volatile("s_waitcnt lgkmcnt(0)" ::: "memory");                  \
    __builtin_amdgcn_s_barrier();                                       \
    __builtin_amdgcn_sched_barrier(0);                                  \
    bf16x8 rf[4];                                                       \
    _Pragma("unroll") for (int kt = 0; kt < 4; ++kt)                    \
        rf[kt] = *(const bf16x8*)&s_rh[rA][kt * 32 + g * 8];            \
    f32x4 acch = AXHC;                                                  \
    if ((t) + 1 < LSEQ) {                                               \
      AXHN = (f32x4){biash, biash, biash, biash};                       \
      _Pragma("unroll") for (int kt = 0; kt < 4; ++kt)                  \
        AXHN = mfma16(__builtin_bit_cast(bf16x8, XC[kt]), wh[kt], AXHN);\
    }                                                                   \
    _Pragma("unroll") for (int kt = 0; kt < 4; ++kt)                    \
      acch = mfma16(rf[kt], wh[4 + kt], acch);                          \
    _Pragma("unroll") for (int j = 0; j < 4; ++j) {                     \
      float ht = fast_tanh(acch[j]);                                    \
      float up = s_att[t][g * 4 + j] * uu[j];                           \
      hD[j] += up * (ht - hD[j]);                                       \
      s_hb[g * 4 + j][col] = (__bf16)hD[j];                             \
    }                                                                   \
    __builtin_amdgcn_sched_barrier(0);                                  \
    asm volatile("s_waitcnt lgkmcnt(0)" ::: "memory");                  \
    __builtin_amdgcn_s_barrier();                                       \
    __builtin_amdgcn_sched_barrier(0);                                  \
  } while (0)

__global__ __launch_bounds__(512, 2) void k_fused(
    const float* __restrict__ h_states, const float* __restrict__ target,
    const int* __restrict__ mask,
    const float* __restrict__ Wr, const float* __restrict__ br,
    const float* __restrict__ Wu, const float* __restrict__ bu,
    const float* __restrict__ Wh, const float* __restrict__ bh,
    uint4* __restrict__ xp, float* __restrict__ out, int B) {
  __shared__ float s_sc[4][16][LSEQ];   // per-kt partial dots (phase 1 only)
  __shared__ float s_tgt[16][DDIM];
  __shared__ float s_att[LSEQ][16];
  __shared__ __bf16 s_rh[16][136];      // pad 128->136: conflict-free b128
  __shared__ __bf16 s_hb[16][136];

  const int b16 = blockIdx.x;
  const int bb = b16 * 16;
  const int tid = threadIdx.x;
  const int lane = tid & 63;
  const int wv = tid >> 6;

  // ---------------- Phase 1: scores + pack x to bf16 A-frags ----------------
  for (int i = tid; i < 16 * DDIM; i += 512)
    s_tgt[i >> 7][i & 127] = target[(size_t)(bb + (i >> 7)) * DDIM + (i & 127)];
  __syncthreads();

  {
    const int kt = (tid >> 6) & 3;
    const int tp = tid >> 8;
    const int row = lane & 15;
    const int hi = lane >> 4;
    const int kbase = kt * 32 + hi * 8;
    const float* src = h_states + ((size_t)(bb + row) * LSEQ) * DDIM + kbase;
    const float* tg = &s_tgt[row][kbase];
#pragma unroll 2
    for (int t = tp; t < LSEQ; t += 2) {
      float4 a = *(const float4*)(src + (size_t)t * DDIM);
      float4 b = *(const float4*)(src + (size_t)t * DDIM + 4);
      float dv = (a.x * tg[0] + a.y * tg[1] + a.z * tg[2] + a.w * tg[3]) +
                 (b.x * tg[4] + b.y * tg[5] + b.z * tg[6] + b.w * tg[7]);
      dv += __shfl_xor(dv, 16);
      dv += __shfl_xor(dv, 32);
      if (hi == 0) s_sc[kt][row][t] = dv;
      union { __bf16 h[8]; uint4 v; } pk;
      pk.h[0] = (__bf16)a.x; pk.h[1] = (__bf16)a.y; pk.h[2] = (__bf16)a.z; pk.h[3] = (__bf16)a.w;
      pk.h[4] = (__bf16)b.x; pk.h[5] = (__bf16)b.y; pk.h[6] = (__bf16)b.z; pk.h[7] = (__bf16)b.w;
      xp[(((size_t)b16 * LSEQ + t) * 4 + kt) * 64 + lane] = pk.v;
    }
  }
  __syncthreads();

  // ---------------- Weights -> bf16 B-frags in VGPRs (all 8 waves) ----------
  const int g = lane >> 4;
  const int rA = lane & 15;
  const int col = wv * 16 + rA;
  bf16x8 wr[8], wu[8], wh[8];
#pragma unroll
  for (int kt = 0; kt < 8; ++kt) {
    bf16x8 tr, tu, th;
    int krow = kt * 32 + g * 8;
#pragma unroll
    for (int j = 0; j < 8; ++j) {
      tr[j] = (__bf16)Wr[(size_t)(krow + j) * DDIM + col];
      tu[j] = (__bf16)Wu[(size_t)(krow + j) * DDIM + col];
      th[j] = (__bf16)Wh[(size_t)(krow + j) * DDIM + col];
    }
    wr[kt] = tr; wu[kt] = tu; wh[kt] = th;
  }
  const float biasr = br[col], biasu = bu[col], biash = bh[col];

  // ---------------- Softmax (256 threads) -> s_att in LDS -------------------
  if (tid < 256) {
    const int r2 = tid >> 4;
    const int j = tid & 15;
    const int* mrow = mask + (size_t)(bb + r2) * LSEQ;
    float mx = -3.0e38f;
    for (int t = j; t < LSEQ; t += 16) {
      float s = (s_sc[0][r2][t] + s_sc[1][r2][t]) + (s_sc[2][r2][t] + s_sc[3][r2][t]);
      s *= 0.088388347648318447f;  // 1/sqrt(128)
      s = (mrow[t] != 0) ? s : -3.0e38f;
      s_sc[0][r2][t] = s;
      mx = fmaxf(mx, s);
    }
    mx = fmaxf(mx, __shfl_xor(mx, 1));
    mx = fmaxf(mx, __shfl_xor(mx, 2));
    mx = fmaxf(mx, __shfl_xor(mx, 4));
    mx = fmaxf(mx, __shfl_xor(mx, 8));
    float se = 0.0f;
    for (int t = j; t < LSEQ; t += 16) {
      float e = fast_exp(s_sc[0][r2][t] - mx);
      s_sc[1][r2][t] = e;
      se += e;
    }
    se += __shfl_xor(se, 1);
    se += __shfl_xor(se, 2);
    se += __shfl_xor(se, 4);
    se += __shfl_xor(se, 8);
    float rs = __builtin_amdgcn_rcpf(se);
    for (int t = j; t < LSEQ; t += 16)
      s_att[t][r2] = (mrow[t] != 0) ? s_sc[1][r2][t] * rs : 0.0f;
  }
  for (int i = tid; i < 16 * 136; i += 512)
    (&s_hb[0][0])[i] = (__bf16)0.0f;

  // ---------------- Recurrence prologue -------------------------------------
  uint4 xT[4], xA[4], xB[4];
  {
    size_t pbase = (size_t)b16 * LSEQ * 4;
#pragma unroll
    for (int kt = 0; kt < 4; ++kt) xT[kt] = xp[(pbase + kt) * 64 + lane];
#pragma unroll
    for (int kt = 0; kt < 4; ++kt) xA[kt] = xp[(pbase + 4 + kt) * 64 + lane];
  }
  f32x4 axr0 = {biasr, biasr, biasr, biasr};
  f32x4 axu0 = {biasu, biasu, biasu, biasu};
  f32x4 axh0 = {biash, biash, biash, biash};
#pragma unroll
  for (int kt = 0; kt < 4; ++kt) {
    bf16x8 a = __builtin_bit_cast(bf16x8, xT[kt]);
    axr0 = mfma16(a, wr[kt], axr0);
    axu0 = mfma16(a, wu[kt], axu0);
    axh0 = mfma16(a, wh[kt], axh0);
  }
  f32x4 axr1, axu1, axh1;
  float hD[4] = {0.f, 0.f, 0.f, 0.f};
  __syncthreads();

  // ---------------- Main serial loop (2x unrolled) --------------------------
  for (int t = 0; t < LSEQ; t += 2) {
    STEP(t, xA, xB, axr0, axu0, axh0, axr1, axu1, axh1);
    STEP(t + 1, xB, xA, axr1, axu1, axh1, axr0, axu0, axh0);
  }

#pragma unroll
  for (int j = 0; j < 4; ++j)
    out[(size_t)(bb + g * 4 + j) * DDIM + col] = hD[j];
}

extern "C" void kernel_launch(void* const* d_in, const int* in_sizes, int n_in,
                              void* d_out, int out_size, void* d_ws, size_t ws_size,
                              hipStream_t stream) {
  const float* h_states = (const float*)d_in[0];
  const float* target   = (const float*)d_in[1];
  const int*   mask     = (const int*)d_in[2];
  const float* Wr = (const float*)d_in[3];
  const float* br = (const float*)d_in[4];
  const float* Wu = (const float*)d_in[5];
  const float* bu = (const float*)d_in[6];
  const float* Wh = (const float*)d_in[7];
  const float* bh = (const float*)d_in[8];

  const int B = in_sizes[0] / (LSEQ * DDIM);  // 4096
  uint4* xp = (uint4*)d_ws;                   // B*L*128 bf16 A-frags

  k_fused<<<B / 16, 512, 0, stream>>>(h_states, target, mask, Wr, br, Wu, bu,
                                      Wh, bh, xp, (float*)d_out, B);
}